// Round 2
// baseline (308.631 us; speedup 1.0000x reference)
//
#include <hip/hip_runtime.h>

// Problem constants: B=16, T=32, NP=8, NG=4, J=14, H=256
#define BT      512          // B*T
#define NP      8
#define NG      4
#define JNT     14
#define NCENTER 33554432     // B*T*H*H
#define NBLK_CENTER 4096     // center-loss blocks; 4096*256 thr * 8 f4 = 8.4M float4
#define WOFF    NBLK_CENTER  // ws offset of Hungarian partials (stride 4 per cell)

// ---------------- partials path (2 kernels, no atomics) ----------------

__global__ __launch_bounds__(256) void main_kernel(
    const float* __restrict__ hm,
    const float* __restrict__ hor_offset,
    const float* __restrict__ hor_bsize,
    const float* __restrict__ hor_center,
    const float* __restrict__ scores,
    const float* __restrict__ x_pose3d,
    const float* __restrict__ gt_hm,
    const float* __restrict__ gt_wh,
    const float* __restrict__ gt_off,
    const float* __restrict__ gt_center,
    const float* __restrict__ gt_pose,
    float* __restrict__ ws,
    int use_atomics)
{
    __shared__ float sC[32];
    __shared__ float sCp[32];
    __shared__ float sv[8];
    __shared__ int   sp[8];

    const int blk = blockIdx.x;
    const int tid = threadIdx.x;

    if (blk < NBLK_CENTER) {
        // ---- center loss: 8 float4-pairs per thread, unrolled for MLP ----
        const float4* a = (const float4*)hm;
        const float4* b = (const float4*)gt_hm;
        const int gsz  = NBLK_CENTER * 256;
        const int base = blk * 256 + tid;
        float s = 0.0f;
        #pragma unroll 4
        for (int k = 0; k < 8; k++) {
            const int i = base + k * gsz;
            float4 x = a[i];
            float4 y = b[i];
            float d0 = x.x - y.x, d1 = x.y - y.y, d2 = x.z - y.z, d3 = x.w - y.w;
            s += d0 * d0 + d1 * d1 + d2 * d2 + d3 * d3;
        }
        #pragma unroll
        for (int o = 32; o > 0; o >>= 1) s += __shfl_down(s, o);
        const int lane = tid & 63, w = tid >> 6;
        if (lane == 0) sv[w] = s;
        __syncthreads();
        if (tid == 0) {
            float tot = sv[0] + sv[1] + sv[2] + sv[3];
            if (use_atomics) atomicAdd(&ws[0], tot);
            else             ws[blk] = tot;
        }
        return;
    }

    // ---- Hungarian matching for one (b,t) cell ----
    const int c = blk - NBLK_CENTER;               // 0..511
    const float* pc = hor_center + c * (NP * 2);
    const float* gc = gt_center  + c * (NG * 2);
    const float* sc = scores     + c * NP;
    const float* po = hor_offset + c * (NP * 2);
    const float* go = gt_off     + c * (NG * 2);
    const float* ps = hor_bsize  + c * (NP * 4);
    const float* gs = gt_wh      + c * (NG * 4);
    const float* pp = x_pose3d   + c * (NP * JNT * 3);
    const float* gp = gt_pose    + c * (NG * JNT * 3);

    if (tid < 32) {
        const int i = tid >> 2;
        const int j = tid & 3;
        float dx = pc[i * 2 + 0] - gc[j * 2 + 0];
        float dy = pc[i * 2 + 1] - gc[j * 2 + 1];
        sC[i * 4 + j] = sqrtf(dx * dx + dy * dy) - sc[i];
        float acc = 0.0f;
        const float* ai = pp + i * (JNT * 3);
        const float* gj = gp + j * (JNT * 3);
        #pragma unroll
        for (int k = 0; k < JNT * 3; k++) {
            float d = ai[k] - gj[k];
            acc += d * d;
        }
        sCp[i * 4 + j] = sqrtf(acc);
    }
    __syncthreads();

    // lexicographic enumeration of 8^4 tuples; injective-only == itertools.permutations order
    float bv = 1e30f, bv2 = 1e30f;
    int bp = 0x7fffffff, bp2 = 0x7fffffff;
    for (int p = tid; p < 4096; p += 256) {
        const int i0 = (p >> 9) & 7, i1 = (p >> 6) & 7, i2 = (p >> 3) & 7, i3 = p & 7;
        if (i0 == i1 || i0 == i2 || i0 == i3 || i1 == i2 || i1 == i3 || i2 == i3) continue;
        float t  = sC [i0 * 4 + 0] + sC [i1 * 4 + 1] + sC [i2 * 4 + 2] + sC [i3 * 4 + 3];
        float t2 = sCp[i0 * 4 + 0] + sCp[i1 * 4 + 1] + sCp[i2 * 4 + 2] + sCp[i3 * 4 + 3];
        if (t  < bv)  { bv  = t;  bp  = p; }
        if (t2 < bv2) { bv2 = t2; bp2 = p; }
    }
    #pragma unroll
    for (int o = 32; o > 0; o >>= 1) {
        float v2 = __shfl_down(bv, o);  int p2 = __shfl_down(bp, o);
        if (v2 < bv  || (v2 == bv  && p2 < bp))  { bv  = v2; bp  = p2; }
        float w2 = __shfl_down(bv2, o); int q2 = __shfl_down(bp2, o);
        if (w2 < bv2 || (w2 == bv2 && q2 < bp2)) { bv2 = w2; bp2 = q2; }
    }
    const int lane = tid & 63, w = tid >> 6;
    if (lane == 0) { sv[w] = bv; sp[w] = bp; sv[4 + w] = bv2; sp[4 + w] = bp2; }
    __syncthreads();

    if (tid == 0) {
        for (int k = 1; k < 4; k++) {
            if (sv[k] < sv[0] || (sv[k] == sv[0] && sp[k] < sp[0])) { sv[0] = sv[k]; sp[0] = sp[k]; }
            if (sv[4 + k] < sv[4] || (sv[4 + k] == sv[4] && sp[4 + k] < sp[4])) { sv[4] = sv[4 + k]; sp[4] = sp[4 + k]; }
        }
        const int pb = sp[0];
        const int pq = sp[4];
        float off = 0.0f, size = 0.0f, pose = 0.0f;
        #pragma unroll
        for (int jj = 0; jj < 4; jj++) {
            const int r = (pb >> (9 - 3 * jj)) & 7;
            off += 0.5f * (fabsf(po[r * 2 + 0] - go[jj * 2 + 0]) +
                           fabsf(po[r * 2 + 1] - go[jj * 2 + 1]));
            size += 0.25f * (fabsf(ps[r * 4 + 0] - gs[jj * 4 + 0]) +
                             fabsf(ps[r * 4 + 1] - gs[jj * 4 + 1]) +
                             fabsf(ps[r * 4 + 2] - gs[jj * 4 + 2]) +
                             fabsf(ps[r * 4 + 3] - gs[jj * 4 + 3]));
            const int r2 = (pq >> (9 - 3 * jj)) & 7;
            const float* ai = pp + r2 * (JNT * 3);
            const float* gj = gp + jj * (JNT * 3);
            for (int k = 0; k < JNT * 3; k++) {
                float d = ai[k] - gj[k];
                pose += d * d;
            }
        }
        if (use_atomics) {
            atomicAdd(&ws[1], off);
            atomicAdd(&ws[2], size);
            atomicAdd(&ws[3], pose);
        } else {
            float* slot = ws + WOFF + c * 4;
            slot[0] = off;
            slot[1] = size;
            slot[2] = pose;
        }
    }
}

__global__ __launch_bounds__(256) void final_partials_kernel(
    const float* __restrict__ ws, float* __restrict__ out)
{
    __shared__ float red[16];
    const int tid = threadIdx.x;
    float s0 = 0.0f, s1 = 0.0f, s2 = 0.0f, s3 = 0.0f;
    for (int i = tid; i < NBLK_CENTER; i += 256) s0 += ws[i];
    for (int c = tid; c < BT; c += 256) {
        const float* slot = ws + WOFF + c * 4;
        s1 += slot[0];
        s2 += slot[1];
        s3 += slot[2];
    }
    #pragma unroll
    for (int o = 32; o > 0; o >>= 1) {
        s0 += __shfl_down(s0, o);
        s1 += __shfl_down(s1, o);
        s2 += __shfl_down(s2, o);
        s3 += __shfl_down(s3, o);
    }
    const int lane = tid & 63, w = tid >> 6;
    if (lane == 0) { red[w] = s0; red[4 + w] = s1; red[8 + w] = s2; red[12 + w] = s3; }
    __syncthreads();
    if (tid == 0) {
        s0 = red[0] + red[1] + red[2] + red[3];
        s1 = red[4] + red[5] + red[6] + red[7];
        s2 = red[8] + red[9] + red[10] + red[11];
        s3 = red[12] + red[13] + red[14] + red[15];
        out[0] = s0 * (1.0f / (float)NCENTER)
               + (s1 + s2) * (1.0f / (float)BT)
               + s3 * (1.0f / (float)(BT * NP * JNT));
    }
}

// ---------------- atomic-path helpers (fallback if ws too small) ----------------

__global__ void init_ws_kernel(float* __restrict__ ws) {
    if (threadIdx.x < 4) ws[threadIdx.x] = 0.0f;
}

__global__ void final_atomic_kernel(const float* __restrict__ ws, float* __restrict__ out) {
    out[0] = ws[0] * (1.0f / (float)NCENTER)
           + (ws[1] + ws[2]) * (1.0f / (float)BT)
           + ws[3] * (1.0f / (float)(BT * NP * JNT));
}

extern "C" void kernel_launch(void* const* d_in, const int* in_sizes, int n_in,
                              void* d_out, int out_size, void* d_ws, size_t ws_size,
                              hipStream_t stream) {
    const float* hm         = (const float*)d_in[0];
    const float* hor_offset = (const float*)d_in[1];
    const float* hor_bsize  = (const float*)d_in[2];
    const float* hor_center = (const float*)d_in[3];
    const float* scores     = (const float*)d_in[4];
    const float* x_pose3d   = (const float*)d_in[5];
    const float* gt_hm      = (const float*)d_in[6];
    const float* gt_wh      = (const float*)d_in[7];
    const float* gt_off     = (const float*)d_in[8];
    const float* gt_center  = (const float*)d_in[9];
    const float* gt_pose    = (const float*)d_in[10];
    float* ws  = (float*)d_ws;
    float* out = (float*)d_out;

    const size_t needed = (size_t)(NBLK_CENTER + 4 * BT) * sizeof(float);
    const int use_atomics = (ws_size < needed) ? 1 : 0;

    if (use_atomics) init_ws_kernel<<<1, 64, 0, stream>>>(ws);
    main_kernel<<<NBLK_CENTER + BT, 256, 0, stream>>>(
        hm, hor_offset, hor_bsize, hor_center, scores, x_pose3d,
        gt_hm, gt_wh, gt_off, gt_center, gt_pose, ws, use_atomics);
    if (use_atomics) final_atomic_kernel<<<1, 1, 0, stream>>>(ws, out);
    else             final_partials_kernel<<<1, 256, 0, stream>>>(ws, out);
}

// Round 3
// 305.377 us; speedup vs baseline: 1.0107x; 1.0107x over previous
//
#include <hip/hip_runtime.h>

// Problem constants: B=16, T=32, NP=8, NG=4, J=14, H=256
#define BT      512          // B*T
#define NP      8
#define NG      4
#define JNT     14
#define NCENTER 33554432     // B*T*H*H
#define N4      8388608      // NCENTER/4
#define CBLK    1024         // center-loss blocks
#define CSTEP   (CBLK*256)   // 262144 float4 = 4 MB stride (R0's known-fastest)
#define HALF4   (N4/2)       // 4194304

// ws layout (partials path): ws[0..CBLK) center partials, ws[CBLK..CBLK+BT) cell losses (pre-scaled)

__global__ __launch_bounds__(256) void center_kernel(
    const float* __restrict__ hm, const float* __restrict__ gt_hm,
    float* __restrict__ ws, int use_atomics)
{
    __shared__ float sv[4];
    const int tid = threadIdx.x;
    const int base = blockIdx.x * 256 + tid;
    const float4* a = (const float4*)hm;
    const float4* b = (const float4*)gt_hm;
    float s0 = 0.0f, s1 = 0.0f;
    for (int k = 0; k < 16; k++) {
        const int i = base + k * CSTEP;
        float4 x0 = a[i];          // two independent streams 64 MB apart:
        float4 y0 = b[i];          // 4 x 16B loads in flight per lane per trip
        float4 x1 = a[i + HALF4];
        float4 y1 = b[i + HALF4];
        float d0 = x0.x - y0.x, d1 = x0.y - y0.y, d2 = x0.z - y0.z, d3 = x0.w - y0.w;
        s0 += d0 * d0 + d1 * d1 + d2 * d2 + d3 * d3;
        float e0 = x1.x - y1.x, e1 = x1.y - y1.y, e2 = x1.z - y1.z, e3 = x1.w - y1.w;
        s1 += e0 * e0 + e1 * e1 + e2 * e2 + e3 * e3;
    }
    float s = s0 + s1;
    #pragma unroll
    for (int o = 32; o > 0; o >>= 1) s += __shfl_down(s, o);
    const int lane = tid & 63, w = tid >> 6;
    if (lane == 0) sv[w] = s;
    __syncthreads();
    if (tid == 0) {
        float tot = sv[0] + sv[1] + sv[2] + sv[3];
        if (use_atomics) atomicAdd(&ws[0], tot);
        else             ws[blockIdx.x] = tot;
    }
}

__global__ __launch_bounds__(256) void hungarian_kernel(
    const float* __restrict__ hor_offset,
    const float* __restrict__ hor_bsize,
    const float* __restrict__ hor_center,
    const float* __restrict__ scores,
    const float* __restrict__ x_pose3d,
    const float* __restrict__ gt_wh,
    const float* __restrict__ gt_off,
    const float* __restrict__ gt_center,
    const float* __restrict__ gt_pose,
    float* __restrict__ ws, int use_atomics)
{
    __shared__ float sPP[NP * JNT * 3];   // 336
    __shared__ float sGP[NG * JNT * 3];   // 168
    __shared__ float sPO[NP * 2];
    __shared__ float sGO[NG * 2];
    __shared__ float sPS[NP * 4];
    __shared__ float sGS[NG * 4];
    __shared__ float sPC[NP * 2];
    __shared__ float sGC[NG * 2];
    __shared__ float sSC[NP];
    __shared__ float2 sCC[NP * NG];       // (box_cost, pose_cost)
    __shared__ float sv[8];
    __shared__ int   spx[8];
    __shared__ int   sBest[2];

    const int c   = blockIdx.x;           // 0..511
    const int tid = threadIdx.x;

    // ---- stage everything into LDS (coalesced, small) ----
    {
        const float* pp = x_pose3d  + c * (NP * JNT * 3);
        const float* gp = gt_pose   + c * (NG * JNT * 3);
        for (int k = tid; k < NP * JNT * 3; k += 256) sPP[k] = pp[k];
        if (tid < NG * JNT * 3) sGP[tid] = gp[tid];
        if (tid < NP * 2) sPO[tid] = hor_offset[c * NP * 2 + tid];
        if (tid < NG * 2) sGO[tid] = gt_off[c * NG * 2 + tid];
        if (tid < NP * 4) sPS[tid] = hor_bsize[c * NP * 4 + tid];
        if (tid < NG * 4) sGS[tid] = gt_wh[c * NG * 4 + tid];
        if (tid < NP * 2) sPC[tid] = hor_center[c * NP * 2 + tid];
        if (tid < NG * 2) sGC[tid] = gt_center[c * NG * 2 + tid];
        if (tid < NP)     sSC[tid] = scores[c * NP + tid];
    }
    __syncthreads();

    // ---- cost matrices (32 lanes) ----
    if (tid < 32) {
        const int i = tid >> 2, j = tid & 3;
        float dx = sPC[i * 2 + 0] - sGC[j * 2 + 0];
        float dy = sPC[i * 2 + 1] - sGC[j * 2 + 1];
        float box = sqrtf(dx * dx + dy * dy) - sSC[i];
        float acc = 0.0f;
        #pragma unroll
        for (int k = 0; k < JNT * 3; k++) {
            float d = sPP[i * (JNT * 3) + k] - sGP[j * (JNT * 3) + k];
            acc += d * d;
        }
        sCC[i * 4 + j] = make_float2(box, sqrtf(acc));
    }
    __syncthreads();

    // ---- enumerate 8^4 lexicographic tuples; injective == itertools.permutations order ----
    float bv = 1e30f, bv2 = 1e30f;
    int bp = 0x7fffffff, bp2 = 0x7fffffff;
    for (int p = tid; p < 4096; p += 256) {
        const int i0 = (p >> 9) & 7, i1 = (p >> 6) & 7, i2 = (p >> 3) & 7, i3 = p & 7;
        if (i0 == i1 || i0 == i2 || i0 == i3 || i1 == i2 || i1 == i3 || i2 == i3) continue;
        float2 t0 = sCC[i0 * 4 + 0], t1 = sCC[i1 * 4 + 1], t2 = sCC[i2 * 4 + 2], t3 = sCC[i3 * 4 + 3];
        float t  = t0.x + t1.x + t2.x + t3.x;
        float u  = t0.y + t1.y + t2.y + t3.y;
        if (t < bv)  { bv  = t; bp  = p; }   // strictly-less keeps lowest p on ties
        if (u < bv2) { bv2 = u; bp2 = p; }
    }
    #pragma unroll
    for (int o = 32; o > 0; o >>= 1) {
        float v2 = __shfl_down(bv, o);  int p2 = __shfl_down(bp, o);
        if (v2 < bv  || (v2 == bv  && p2 < bp))  { bv  = v2; bp  = p2; }
        float w2 = __shfl_down(bv2, o); int q2 = __shfl_down(bp2, o);
        if (w2 < bv2 || (w2 == bv2 && q2 < bp2)) { bv2 = w2; bp2 = q2; }
    }
    const int lane = tid & 63, w = tid >> 6;
    if (lane == 0) { sv[w] = bv; spx[w] = bp; sv[4 + w] = bv2; spx[4 + w] = bp2; }
    __syncthreads();
    if (tid == 0) {
        for (int k = 1; k < 4; k++) {
            if (sv[k] < sv[0] || (sv[k] == sv[0] && spx[k] < spx[0])) { sv[0] = sv[k]; spx[0] = spx[k]; }
            if (sv[4 + k] < sv[4] || (sv[4 + k] == sv[4] && spx[4 + k] < spx[4])) { sv[4] = sv[4 + k]; spx[4] = spx[4 + k]; }
        }
        sBest[0] = spx[0];
        sBest[1] = spx[4];
    }
    __syncthreads();

    // ---- parallel epilogue on wave 0; pre-scaled single partial per cell ----
    if (tid < 64) {
        const int pb = sBest[0], pq = sBest[1];
        float contrib = 0.0f;
        if (tid < JNT * 3) {      // pose: lanes 0..41, element tid of each of the 4 matched pairs
            float acc = 0.0f;
            #pragma unroll
            for (int jj = 0; jj < 4; jj++) {
                const int r2 = (pq >> (9 - 3 * jj)) & 7;
                float d = sPP[r2 * (JNT * 3) + tid] - sGP[jj * (JNT * 3) + tid];
                acc += d * d;
            }
            contrib += acc * (1.0f / (float)(BT * NP * JNT));
        }
        if (tid < 8) {            // offset: jj=tid>>1, comp=tid&1
            const int jj = tid >> 1, cm = tid & 1;
            const int r = (pb >> (9 - 3 * jj)) & 7;
            contrib += 0.5f * fabsf(sPO[r * 2 + cm] - sGO[jj * 2 + cm]) * (1.0f / (float)BT);
        }
        if (tid < 16) {           // size: jj=tid>>2, comp=tid&3
            const int jj = tid >> 2, cm = tid & 3;
            const int r = (pb >> (9 - 3 * jj)) & 7;
            contrib += 0.25f * fabsf(sPS[r * 4 + cm] - sGS[jj * 4 + cm]) * (1.0f / (float)BT);
        }
        #pragma unroll
        for (int o = 32; o > 0; o >>= 1) contrib += __shfl_down(contrib, o);
        if (tid == 0) {
            if (use_atomics) atomicAdd(&ws[1], contrib);
            else             ws[CBLK + c] = contrib;
        }
    }
}

__global__ __launch_bounds__(256) void final_partials_kernel(
    const float* __restrict__ ws, float* __restrict__ out)
{
    __shared__ float red[8];
    const int tid = threadIdx.x;
    float s0 = 0.0f, s1 = 0.0f;
    for (int i = tid; i < CBLK; i += 256) s0 += ws[i];
    for (int c = tid; c < BT; c += 256)   s1 += ws[CBLK + c];
    #pragma unroll
    for (int o = 32; o > 0; o >>= 1) {
        s0 += __shfl_down(s0, o);
        s1 += __shfl_down(s1, o);
    }
    const int lane = tid & 63, w = tid >> 6;
    if (lane == 0) { red[w] = s0; red[4 + w] = s1; }
    __syncthreads();
    if (tid == 0) {
        s0 = red[0] + red[1] + red[2] + red[3];
        s1 = red[4] + red[5] + red[6] + red[7];
        out[0] = s0 * (1.0f / (float)NCENTER) + s1;
    }
}

__global__ void init_ws_kernel(float* __restrict__ ws) {
    if (threadIdx.x < 2) ws[threadIdx.x] = 0.0f;
}

__global__ void final_atomic_kernel(const float* __restrict__ ws, float* __restrict__ out) {
    out[0] = ws[0] * (1.0f / (float)NCENTER) + ws[1];
}

extern "C" void kernel_launch(void* const* d_in, const int* in_sizes, int n_in,
                              void* d_out, int out_size, void* d_ws, size_t ws_size,
                              hipStream_t stream) {
    const float* hm         = (const float*)d_in[0];
    const float* hor_offset = (const float*)d_in[1];
    const float* hor_bsize  = (const float*)d_in[2];
    const float* hor_center = (const float*)d_in[3];
    const float* scores     = (const float*)d_in[4];
    const float* x_pose3d   = (const float*)d_in[5];
    const float* gt_hm      = (const float*)d_in[6];
    const float* gt_wh      = (const float*)d_in[7];
    const float* gt_off     = (const float*)d_in[8];
    const float* gt_center  = (const float*)d_in[9];
    const float* gt_pose    = (const float*)d_in[10];
    float* ws  = (float*)d_ws;
    float* out = (float*)d_out;

    const size_t needed = (size_t)(CBLK + BT) * sizeof(float);
    const int use_atomics = (ws_size < needed) ? 1 : 0;

    if (use_atomics) init_ws_kernel<<<1, 64, 0, stream>>>(ws);
    hungarian_kernel<<<BT, 256, 0, stream>>>(
        hor_offset, hor_bsize, hor_center, scores, x_pose3d,
        gt_wh, gt_off, gt_center, gt_pose, ws, use_atomics);
    center_kernel<<<CBLK, 256, 0, stream>>>(hm, gt_hm, ws, use_atomics);
    if (use_atomics) final_atomic_kernel<<<1, 1, 0, stream>>>(ws, out);
    else             final_partials_kernel<<<1, 256, 0, stream>>>(ws, out);
}

// Round 4
// 297.485 us; speedup vs baseline: 1.0375x; 1.0265x over previous
//
#include <hip/hip_runtime.h>

// Problem constants: B=16, T=32, NP=8, NG=4, J=14, H=256
#define BT      512          // B*T
#define NP      8
#define NG      4
#define JNT     14
#define NCENTER 33554432     // B*T*H*H
#define N4      8388608      // NCENTER/4 (float4 count per array)
#define CBLK    2048         // center blocks
#define PER_BLK 4096         // float4 per array per block (contiguous 64 KB)

// ws layout (partials): ws[0..BT) hungarian cell partials (pre-scaled),
//                       ws[BT..BT+CBLK) center partials

__global__ __launch_bounds__(256) void fused_kernel(
    const float* __restrict__ hm,
    const float* __restrict__ hor_offset,
    const float* __restrict__ hor_bsize,
    const float* __restrict__ hor_center,
    const float* __restrict__ scores,
    const float* __restrict__ x_pose3d,
    const float* __restrict__ gt_hm,
    const float* __restrict__ gt_wh,
    const float* __restrict__ gt_off,
    const float* __restrict__ gt_center,
    const float* __restrict__ gt_pose,
    float* __restrict__ ws, int use_atomics)
{
    __shared__ float sPP[NP * JNT * 3];
    __shared__ float sGP[NG * JNT * 3];
    __shared__ float sPO[NP * 2];
    __shared__ float sGO[NG * 2];
    __shared__ float sPS[NP * 4];
    __shared__ float sGS[NG * 4];
    __shared__ float sPC[NP * 2];
    __shared__ float sGC[NG * 2];
    __shared__ float sSC[NP];
    __shared__ float2 sCC[NP * NG];
    __shared__ float sv[8];
    __shared__ int   spx[8];
    __shared__ int   sBest[2];

    const int blk = blockIdx.x;
    const int tid = threadIdx.x;

    if (blk >= BT) {
        // ---------------- center loss: contiguous 64 KB/block/array ----------------
        const int cb = blk - BT;                 // 0..CBLK-1
        const float4* a = (const float4*)hm;
        const float4* b = (const float4*)gt_hm;
        const int base = cb * PER_BLK + tid;
        float s = 0.0f;
        #pragma unroll
        for (int batch = 0; batch < 4; batch++) {
            float4 xa[4], xb[4];
            #pragma unroll
            for (int r = 0; r < 4; r++) xa[r] = a[base + batch * 1024 + r * 256];
            #pragma unroll
            for (int r = 0; r < 4; r++) xb[r] = b[base + batch * 1024 + r * 256];
            #pragma unroll
            for (int r = 0; r < 4; r++) {
                float d0 = xa[r].x - xb[r].x;
                float d1 = xa[r].y - xb[r].y;
                float d2 = xa[r].z - xb[r].z;
                float d3 = xa[r].w - xb[r].w;
                s += d0 * d0 + d1 * d1 + d2 * d2 + d3 * d3;
            }
        }
        #pragma unroll
        for (int o = 32; o > 0; o >>= 1) s += __shfl_down(s, o);
        const int lane = tid & 63, w = tid >> 6;
        if (lane == 0) sv[w] = s;
        __syncthreads();
        if (tid == 0) {
            float tot = sv[0] + sv[1] + sv[2] + sv[3];
            if (use_atomics) atomicAdd(&ws[0], tot);
            else             ws[BT + cb] = tot;
        }
        return;
    }

    // ---------------- Hungarian matching for one (b,t) cell ----------------
    const int c = blk;                            // 0..511
    {
        const float* pp = x_pose3d + c * (NP * JNT * 3);
        const float* gp = gt_pose  + c * (NG * JNT * 3);
        for (int k = tid; k < NP * JNT * 3; k += 256) sPP[k] = pp[k];
        if (tid < NG * JNT * 3) sGP[tid] = gp[tid];
        if (tid < NP * 2) sPO[tid] = hor_offset[c * NP * 2 + tid];
        if (tid < NG * 2) sGO[tid] = gt_off[c * NG * 2 + tid];
        if (tid < NP * 4) sPS[tid] = hor_bsize[c * NP * 4 + tid];
        if (tid < NG * 4) sGS[tid] = gt_wh[c * NG * 4 + tid];
        if (tid < NP * 2) sPC[tid] = hor_center[c * NP * 2 + tid];
        if (tid < NG * 2) sGC[tid] = gt_center[c * NG * 2 + tid];
        if (tid < NP)     sSC[tid] = scores[c * NP + tid];
    }
    __syncthreads();

    if (tid < 32) {
        const int i = tid >> 2, j = tid & 3;
        float dx = sPC[i * 2 + 0] - sGC[j * 2 + 0];
        float dy = sPC[i * 2 + 1] - sGC[j * 2 + 1];
        float box = sqrtf(dx * dx + dy * dy) - sSC[i];
        float acc = 0.0f;
        #pragma unroll
        for (int k = 0; k < JNT * 3; k++) {
            float d = sPP[i * (JNT * 3) + k] - sGP[j * (JNT * 3) + k];
            acc += d * d;
        }
        sCC[i * 4 + j] = make_float2(box, sqrtf(acc));
    }
    __syncthreads();

    // lexicographic 8^4 enumeration; injective-only == itertools.permutations order
    float bv = 1e30f, bv2 = 1e30f;
    int bp = 0x7fffffff, bp2 = 0x7fffffff;
    for (int p = tid; p < 4096; p += 256) {
        const int i0 = (p >> 9) & 7, i1 = (p >> 6) & 7, i2 = (p >> 3) & 7, i3 = p & 7;
        if (i0 == i1 || i0 == i2 || i0 == i3 || i1 == i2 || i1 == i3 || i2 == i3) continue;
        float2 t0 = sCC[i0 * 4 + 0], t1 = sCC[i1 * 4 + 1], t2 = sCC[i2 * 4 + 2], t3 = sCC[i3 * 4 + 3];
        float t = t0.x + t1.x + t2.x + t3.x;
        float u = t0.y + t1.y + t2.y + t3.y;
        if (t < bv)  { bv  = t; bp  = p; }
        if (u < bv2) { bv2 = u; bp2 = p; }
    }
    #pragma unroll
    for (int o = 32; o > 0; o >>= 1) {
        float v2 = __shfl_down(bv, o);  int p2 = __shfl_down(bp, o);
        if (v2 < bv  || (v2 == bv  && p2 < bp))  { bv  = v2; bp  = p2; }
        float w2 = __shfl_down(bv2, o); int q2 = __shfl_down(bp2, o);
        if (w2 < bv2 || (w2 == bv2 && q2 < bp2)) { bv2 = w2; bp2 = q2; }
    }
    const int lane = tid & 63, w = tid >> 6;
    if (lane == 0) { sv[w] = bv; spx[w] = bp; sv[4 + w] = bv2; spx[4 + w] = bp2; }
    __syncthreads();
    if (tid == 0) {
        for (int k = 1; k < 4; k++) {
            if (sv[k] < sv[0] || (sv[k] == sv[0] && spx[k] < spx[0])) { sv[0] = sv[k]; spx[0] = spx[k]; }
            if (sv[4 + k] < sv[4] || (sv[4 + k] == sv[4] && spx[4 + k] < spx[4])) { sv[4] = sv[4 + k]; spx[4] = spx[4 + k]; }
        }
        sBest[0] = spx[0];
        sBest[1] = spx[4];
    }
    __syncthreads();

    if (tid < 64) {
        const int pb = sBest[0], pq = sBest[1];
        float contrib = 0.0f;
        if (tid < JNT * 3) {
            float acc = 0.0f;
            #pragma unroll
            for (int jj = 0; jj < 4; jj++) {
                const int r2 = (pq >> (9 - 3 * jj)) & 7;
                float d = sPP[r2 * (JNT * 3) + tid] - sGP[jj * (JNT * 3) + tid];
                acc += d * d;
            }
            contrib += acc * (1.0f / (float)(BT * NP * JNT));
        }
        if (tid < 8) {
            const int jj = tid >> 1, cm = tid & 1;
            const int r = (pb >> (9 - 3 * jj)) & 7;
            contrib += 0.5f * fabsf(sPO[r * 2 + cm] - sGO[jj * 2 + cm]) * (1.0f / (float)BT);
        }
        if (tid < 16) {
            const int jj = tid >> 2, cm = tid & 3;
            const int r = (pb >> (9 - 3 * jj)) & 7;
            contrib += 0.25f * fabsf(sPS[r * 4 + cm] - sGS[jj * 4 + cm]) * (1.0f / (float)BT);
        }
        #pragma unroll
        for (int o = 32; o > 0; o >>= 1) contrib += __shfl_down(contrib, o);
        if (tid == 0) {
            if (use_atomics) atomicAdd(&ws[1], contrib);
            else             ws[c] = contrib;
        }
    }
}

__global__ __launch_bounds__(256) void final_partials_kernel(
    const float* __restrict__ ws, float* __restrict__ out)
{
    __shared__ float red[8];
    const int tid = threadIdx.x;
    float s0 = 0.0f, s1 = 0.0f;
    for (int i = tid; i < CBLK; i += 256) s0 += ws[BT + i];
    for (int c = tid; c < BT; c += 256)   s1 += ws[c];
    #pragma unroll
    for (int o = 32; o > 0; o >>= 1) {
        s0 += __shfl_down(s0, o);
        s1 += __shfl_down(s1, o);
    }
    const int lane = tid & 63, w = tid >> 6;
    if (lane == 0) { red[w] = s0; red[4 + w] = s1; }
    __syncthreads();
    if (tid == 0) {
        s0 = red[0] + red[1] + red[2] + red[3];
        s1 = red[4] + red[5] + red[6] + red[7];
        out[0] = s0 * (1.0f / (float)NCENTER) + s1;
    }
}

__global__ void init_ws_kernel(float* __restrict__ ws) {
    if (threadIdx.x < 2) ws[threadIdx.x] = 0.0f;
}

__global__ void final_atomic_kernel(const float* __restrict__ ws, float* __restrict__ out) {
    out[0] = ws[0] * (1.0f / (float)NCENTER) + ws[1];
}

extern "C" void kernel_launch(void* const* d_in, const int* in_sizes, int n_in,
                              void* d_out, int out_size, void* d_ws, size_t ws_size,
                              hipStream_t stream) {
    const float* hm         = (const float*)d_in[0];
    const float* hor_offset = (const float*)d_in[1];
    const float* hor_bsize  = (const float*)d_in[2];
    const float* hor_center = (const float*)d_in[3];
    const float* scores     = (const float*)d_in[4];
    const float* x_pose3d   = (const float*)d_in[5];
    const float* gt_hm      = (const float*)d_in[6];
    const float* gt_wh      = (const float*)d_in[7];
    const float* gt_off     = (const float*)d_in[8];
    const float* gt_center  = (const float*)d_in[9];
    const float* gt_pose    = (const float*)d_in[10];
    float* ws  = (float*)d_ws;
    float* out = (float*)d_out;

    const size_t needed = (size_t)(BT + CBLK) * sizeof(float);
    const int use_atomics = (ws_size < needed) ? 1 : 0;

    if (use_atomics) init_ws_kernel<<<1, 64, 0, stream>>>(ws);
    fused_kernel<<<BT + CBLK, 256, 0, stream>>>(
        hm, hor_offset, hor_bsize, hor_center, scores, x_pose3d,
        gt_hm, gt_wh, gt_off, gt_center, gt_pose, ws, use_atomics);
    if (use_atomics) final_atomic_kernel<<<1, 1, 0, stream>>>(ws, out);
    else             final_partials_kernel<<<1, 256, 0, stream>>>(ws, out);
}